// Round 19
// baseline (32.744 us; speedup 1.0000x reference)
//
#include <hip/hip_runtime.h>
#include <math.h>

#define BB 32
#define TT 512
#define FF 512
#define HH 1024
#define CC 1000
#define QQ (4*HH)    // 4096 gate columns
#define KCN 4        // fc k-split chunks (256 k each)

// ---------------- Stage 1 (fused): gate partials, 512-thread blocks ----------------
// First 2*CHH blocks: h0 part (2048 cols/block, JCH rows/chunk).
// Next 16*CHD blocks: data part (256 cols x 32 batches, JCD rows/chunk).
template<int JCH, int CHH, int JCD, int CHD>
__global__ __launch_bounds__(512, 4) void k_gates(
    const float* __restrict__ data, const float* __restrict__ h0,
    const float* __restrict__ wf, const float* __restrict__ wi,
    const float* __restrict__ wc, const float* __restrict__ wo,
    float* __restrict__ hp, float* __restrict__ dp)
{
    constexpr int LDSN = (BB*JCD > JCH) ? BB*JCD : JCH;
    __shared__ float lds[LDSN];
    const int t  = threadIdx.x;
    const int bx = blockIdx.x;
    constexpr int NH0 = 2*CHH;

    if (bx < NH0) {
        // ---- h0 part: 2048 cols, JCH rows per chunk ----
        const int cb2 = bx & 1;               // 2048-col half
        const int ch  = bx >> 1;              // row chunk
        const int q   = cb2*2048 + t*4;       // global gate col
        const int gate = q >> 10;             // wave-uniform
        const int k4   = q & (HH-1);
        const float* w = (gate==0) ? wf : (gate==1) ? wi : (gate==2) ? wc : wo;
        if (t < JCH) lds[t] = h0[ch*JCH + t];
        __syncthreads();
        float4 s = make_float4(0.f,0.f,0.f,0.f);
        #pragma unroll
        for (int j = 0; j < JCH; j += 4) {
            const float4 w0 = *(const float4*)(w + (size_t)(ch*JCH + j+0)*HH + k4);
            const float4 w1 = *(const float4*)(w + (size_t)(ch*JCH + j+1)*HH + k4);
            const float4 w2 = *(const float4*)(w + (size_t)(ch*JCH + j+2)*HH + k4);
            const float4 w3 = *(const float4*)(w + (size_t)(ch*JCH + j+3)*HH + k4);
            const float h0v = lds[j+0], h1v = lds[j+1], h2v = lds[j+2], h3v = lds[j+3];
            s.x += h0v*w0.x; s.y += h0v*w0.y; s.z += h0v*w0.z; s.w += h0v*w0.w;
            s.x += h1v*w1.x; s.y += h1v*w1.y; s.z += h1v*w1.z; s.w += h1v*w1.w;
            s.x += h2v*w2.x; s.y += h2v*w2.y; s.z += h2v*w2.z; s.w += h2v*w2.w;
            s.x += h3v*w3.x; s.y += h3v*w3.y; s.z += h3v*w3.z; s.w += h3v*w3.w;
        }
        *(float4*)(hp + (size_t)ch*QQ + q) = s;
    } else {
        // ---- data part ----
        const int idx  = bx - NH0;
        const int cb   = idx & 15;            // 256-col block
        const int cd   = idx >> 4;            // j-chunk
        const int q0   = cb*256;
        const int gate = q0 >> 10;            // block-uniform
        const int k0   = q0 & (HH-1);
        const float* w = (gate==0) ? wf : (gate==1) ? wi : (gate==2) ? wc : wo;
        const int jc0  = cd*JCD;

        for (int s = t; s < BB*JCD/4; s += 512) {
            const int b  = s / (JCD/4);
            const int jj = (s % (JCD/4))*4;
            const float4 v = *(const float4*)(data + (size_t)b*TT*FF + (size_t)(TT-1)*FF + jc0 + jj);
            lds[b*JCD + jj+0] = v.x; lds[b*JCD + jj+1] = v.y;
            lds[b*JCD + jj+2] = v.z; lds[b*JCD + jj+3] = v.w;
        }
        __syncthreads();

        const int c4 = t & 63;                // 4-col group
        const int b0 = (t >> 6) * 4;          // 4-batch group
        const int k4 = k0 + c4*4;
        float4 acc[4];
        #pragma unroll
        for (int bi = 0; bi < 4; ++bi) acc[bi] = make_float4(0.f,0.f,0.f,0.f);

        #pragma unroll 2
        for (int j = 0; j < JCD; j += 4) {
            const float4 w0 = *(const float4*)(w + (size_t)(HH + jc0 + j+0)*HH + k4);
            const float4 w1 = *(const float4*)(w + (size_t)(HH + jc0 + j+1)*HH + k4);
            const float4 w2 = *(const float4*)(w + (size_t)(HH + jc0 + j+2)*HH + k4);
            const float4 w3 = *(const float4*)(w + (size_t)(HH + jc0 + j+3)*HH + k4);
            #pragma unroll
            for (int bi = 0; bi < 4; ++bi) {
                const float d0 = lds[(b0+bi)*JCD + j+0];
                const float d1 = lds[(b0+bi)*JCD + j+1];
                const float d2 = lds[(b0+bi)*JCD + j+2];
                const float d3 = lds[(b0+bi)*JCD + j+3];
                acc[bi].x += d0*w0.x; acc[bi].y += d0*w0.y; acc[bi].z += d0*w0.z; acc[bi].w += d0*w0.w;
                acc[bi].x += d1*w1.x; acc[bi].y += d1*w1.y; acc[bi].z += d1*w1.z; acc[bi].w += d1*w1.w;
                acc[bi].x += d2*w2.x; acc[bi].y += d2*w2.y; acc[bi].z += d2*w2.z; acc[bi].w += d2*w2.w;
                acc[bi].x += d3*w3.x; acc[bi].y += d3*w3.y; acc[bi].z += d3*w3.z; acc[bi].w += d3*w3.w;
            }
        }
        #pragma unroll
        for (int bi = 0; bi < 4; ++bi)
            *(float4*)(dp + ((size_t)cd*BB + b0 + bi)*QQ + q0 + c4*4) = acc[bi];
    }
}

// ---------------- Stage 2 (fused): cell reduce + fc partial matvec ----------------
// grid = (KCN=4 kc, BB=32 b, 2 c-half), block = 256. Block: (1) reduce gate
// partials for (b, 256-k slice) + activations -> hl_s in LDS (no global hl!);
// (2) matvec 500 cols: 8-lane groups, coalesced float4 fcw reads, hl_s
// broadcast, in-group shfl reduce -> pl[(kc*BB+b)*CC + c].
template<int CH, int CD>
__global__ __launch_bounds__(256, 2) void k_cellfc(
    const float* __restrict__ hp, const float* __restrict__ dp,
    const float* __restrict__ c0, const float* __restrict__ fcw,
    float* __restrict__ pl)
{
    __shared__ float4 p[4][64];
    __shared__ __align__(16) float hl_s[256];
    const int t  = threadIdx.x;
    const int kc = blockIdx.x;                // k-slice 256
    const int b  = blockIdx.y;                // batch
    const int cz = blockIdx.z;                // c-half
    const int g  = t >> 6;
    const int i  = t & 63;
    const int q  = g*HH + kc*256 + i*4;

    float4 s = make_float4(0.f,0.f,0.f,0.f);
    #pragma unroll 8
    for (int ch = 0; ch < CH; ++ch) {
        const float4 v = *(const float4*)(hp + (size_t)ch*QQ + q);
        s.x += v.x; s.y += v.y; s.z += v.z; s.w += v.w;
    }
    #pragma unroll 8
    for (int cd = 0; cd < CD; ++cd) {
        const float4 v = *(const float4*)(dp + ((size_t)cd*BB + b)*QQ + q);
        s.x += v.x; s.y += v.y; s.z += v.z; s.w += v.w;
    }
    p[g][i] = s;
    __syncthreads();

    if (t < 64) {
        const float4 gf = p[0][t], gi4 = p[1][t], gc = p[2][t], go = p[3][t];
        const float4 cv = *(const float4*)(c0 + kc*256 + t*4);
        float4 h;
        { const float f=1.f/(1.f+expf(-gf.x)), ii=1.f/(1.f+expf(-gi4.x)), cg=tanhf(gc.x), o=1.f/(1.f+expf(-go.x)); h.x=o*tanhf(f*cv.x+ii*cg); }
        { const float f=1.f/(1.f+expf(-gf.y)), ii=1.f/(1.f+expf(-gi4.y)), cg=tanhf(gc.y), o=1.f/(1.f+expf(-go.y)); h.y=o*tanhf(f*cv.y+ii*cg); }
        { const float f=1.f/(1.f+expf(-gf.z)), ii=1.f/(1.f+expf(-gi4.z)), cg=tanhf(gc.z), o=1.f/(1.f+expf(-go.z)); h.z=o*tanhf(f*cv.z+ii*cg); }
        { const float f=1.f/(1.f+expf(-gf.w)), ii=1.f/(1.f+expf(-gi4.w)), cg=tanhf(gc.w), o=1.f/(1.f+expf(-go.w)); h.w=o*tanhf(f*cv.w+ii*cg); }
        *(float4*)&hl_s[t*4] = h;
    }
    __syncthreads();

    // ---- fc partial matvec: 32 groups x 8 lanes; 16 col-iters per c-half ----
    const int gi = t >> 3;                    // group 0..31 -> col offset
    const int l8 = t & 7;                     // lane in group -> k split
    for (int m = cz*16; m < cz*16 + 16; ++m) {
        const int c = m*32 + gi;
        if (c < CC) {
            const float4* wr = (const float4*)(fcw + (size_t)c*HH + kc*256);
            float acc = 0.f;
            #pragma unroll
            for (int m8 = 0; m8 < 8; ++m8) {
                const float4 w4 = wr[l8 + m8*8];
                const float4 h4 = *(const float4*)&hl_s[(l8 + m8*8)*4];
                acc += w4.x*h4.x + w4.y*h4.y + w4.z*h4.z + w4.w*h4.w;
            }
            acc += __shfl_xor(acc, 1, 64);
            acc += __shfl_xor(acc, 2, 64);
            acc += __shfl_xor(acc, 4, 64);
            if (l8 == 0) pl[((size_t)kc*BB + b)*CC + c] = acc;
        }
    }
}

// ---------------- Stage 3: reduce k-split + bias + relu + log_softmax ----------------
// grid = (BB), block = 1024 (1 col per thread).
__global__ __launch_bounds__(1024) void k_lsm(
    const float* __restrict__ pl, const float* __restrict__ fcb,
    float* __restrict__ out)
{
    __shared__ float red[20];
    const int b = blockIdx.x, t = threadIdx.x;
    const int w = t >> 6, l = t & 63;
    float v = -1e30f;
    if (t < CC) {
        float s = fcb[t];
        #pragma unroll
        for (int kc = 0; kc < KCN; ++kc)
            s += pl[((size_t)kc*BB + b)*CC + t];
        v = fmaxf(s, 0.f);
    }
    float m = v;
    for (int o = 32; o > 0; o >>= 1) m = fmaxf(m, __shfl_xor(m, o, 64));
    if (l == 0) red[w] = m;
    __syncthreads();
    if (t == 0) {
        float mm = red[0];
        #pragma unroll
        for (int ww = 1; ww < 16; ++ww) mm = fmaxf(mm, red[ww]);
        red[16] = mm;
    }
    __syncthreads();
    const float mb = red[16];
    float se = (t < CC) ? expf(v - mb) : 0.f;
    for (int o = 32; o > 0; o >>= 1) se += __shfl_xor(se, o, 64);
    if (l == 0) red[w] = se;
    __syncthreads();
    if (t == 0) {
        float ss = 0.f;
        #pragma unroll
        for (int ww = 0; ww < 16; ++ww) ss += red[ww];
        red[17] = mb + logf(ss);
    }
    __syncthreads();
    if (t < CC) out[(size_t)b*CC + t] = v - red[17];
}

extern "C" void kernel_launch(void* const* d_in, const int* in_sizes, int n_in,
                              void* d_out, int out_size, void* d_ws, size_t ws_size,
                              hipStream_t stream) {
    const float* data = (const float*)d_in[0];
    const float* h0   = (const float*)d_in[1];
    const float* c0   = (const float*)d_in[2];
    const float* wf   = (const float*)d_in[3];
    const float* wi   = (const float*)d_in[4];
    const float* wc   = (const float*)d_in[5];
    const float* wo   = (const float*)d_in[6];
    const float* fcw  = (const float*)d_in[7];
    const float* fcb  = (const float*)d_in[8];
    float* out = (float*)d_out;

    // Config A: CH_H=32 (JCH=32), CH_D=16 (JCD=32) -> ~9.1 MB ws.
    // Config B: CH_H=32 (JCH=32), CH_D=4  (JCD=128) -> ~3.2 MB ws (fallback).
    const size_t needA = ((size_t)32*QQ + (size_t)16*BB*QQ + (size_t)KCN*BB*CC) * 4;
    const bool cfgA = (ws_size >= needA);

    float* ws = (float*)d_ws;
    if (cfgA) {
        float* hp = ws;                               // 32*QQ
        float* dp = hp + (size_t)32*QQ;               // 16*BB*QQ
        float* pl = dp + (size_t)16*BB*QQ;            // KCN*BB*CC
        k_gates<32,32,32,16><<<dim3(2*32 + 16*16), 512, 0, stream>>>(data, h0, wf, wi, wc, wo, hp, dp);
        k_cellfc<32,16><<<dim3(KCN, BB, 2), 256, 0, stream>>>(hp, dp, c0, fcw, pl);
        k_lsm<<<dim3(BB), 1024, 0, stream>>>(pl, fcb, out);
    } else {
        float* hp = ws;                               // 32*QQ
        float* dp = hp + (size_t)32*QQ;               // 4*BB*QQ
        float* pl = dp + (size_t)4*BB*QQ;             // KCN*BB*CC
        k_gates<32,32,128,4><<<dim3(2*32 + 16*4), 512, 0, stream>>>(data, h0, wf, wi, wc, wo, hp, dp);
        k_cellfc<32,4><<<dim3(KCN, BB, 2), 256, 0, stream>>>(hp, dp, c0, fcw, pl);
        k_lsm<<<dim3(BB), 1024, 0, stream>>>(pl, fcb, out);
    }
}

// Round 20
// 31.651 us; speedup vs baseline: 1.0345x; 1.0345x over previous
//
#include <hip/hip_runtime.h>
#include <math.h>

#define BB 32
#define TT 512
#define FF 512
#define HH 1024
#define CC 1000
#define QQ (4*HH)    // 4096 gate columns
#define FCB 8        // fc columns per block
#define KCN 8        // fc k-split chunks
#define KS  (HH/KCN) // 128 k per chunk

// ---------------- Stage 1: gate partials, column-split for parallelism ----------------
// First 8*CHH blocks: h0 part (512 cols/block, 32 rows/chunk, 4 row-groups + LDS combine).
// Next 32*CHD blocks: data part (128 cols x 32 batches, JCD rows/chunk).
// Partial-array shapes (hp: CHH chunks, dp: CHD chunks) are UNCHANGED vs round 18.
template<int CHH, int JCD, int CHD>
__global__ __launch_bounds__(512, 4) void k_gates(
    const float* __restrict__ data, const float* __restrict__ h0,
    const float* __restrict__ wf, const float* __restrict__ wi,
    const float* __restrict__ wc, const float* __restrict__ wo,
    float* __restrict__ hp, float* __restrict__ dp)
{
    constexpr int LDSH = 32 + 4*128*4;    // h0s + pg[4][128] float4
    constexpr int LDSN = (BB*JCD > LDSH) ? BB*JCD : LDSH;
    __shared__ __align__(16) float lds[LDSN];
    const int t  = threadIdx.x;
    const int bx = blockIdx.x;
    constexpr int NH0 = 8*CHH;            // 256 h0 blocks

    if (bx < NH0) {
        // ---- h0 part: 512 cols, 32 rows; 4 row-groups of 8, LDS combine ----
        const int cb8 = bx & 7;           // 512-col block
        const int ch  = bx >> 3;          // row chunk (32 rows)
        const int q0  = cb8*512;
        const int gate = q0 >> 10;        // block-uniform
        const int k0   = q0 & (HH-1);
        const float* w = (gate==0) ? wf : (gate==1) ? wi : (gate==2) ? wc : wo;
        if (t < 32) lds[t] = h0[ch*32 + t];
        __syncthreads();
        const int lane = t & 127;
        const int rg   = t >> 7;          // row group 0..3
        const int k4   = k0 + lane*4;
        const int j0   = rg*8;
        float4 s = make_float4(0.f,0.f,0.f,0.f);
        #pragma unroll
        for (int j = 0; j < 8; j += 4) {
            const float4 w0 = *(const float4*)(w + (size_t)(ch*32 + j0 + j+0)*HH + k4);
            const float4 w1 = *(const float4*)(w + (size_t)(ch*32 + j0 + j+1)*HH + k4);
            const float4 w2 = *(const float4*)(w + (size_t)(ch*32 + j0 + j+2)*HH + k4);
            const float4 w3 = *(const float4*)(w + (size_t)(ch*32 + j0 + j+3)*HH + k4);
            const float h0v = lds[j0+j+0], h1v = lds[j0+j+1];
            const float h2v = lds[j0+j+2], h3v = lds[j0+j+3];
            s.x += h0v*w0.x; s.y += h0v*w0.y; s.z += h0v*w0.z; s.w += h0v*w0.w;
            s.x += h1v*w1.x; s.y += h1v*w1.y; s.z += h1v*w1.z; s.w += h1v*w1.w;
            s.x += h2v*w2.x; s.y += h2v*w2.y; s.z += h2v*w2.z; s.w += h2v*w2.w;
            s.x += h3v*w3.x; s.y += h3v*w3.y; s.z += h3v*w3.z; s.w += h3v*w3.w;
        }
        float4* pg = (float4*)(lds + 32); // 16B-aligned (32 floats = 128 B)
        pg[rg*128 + lane] = s;
        __syncthreads();
        if (t < 128) {
            const float4 a0 = pg[t], a1 = pg[128+t], a2 = pg[256+t], a3 = pg[384+t];
            float4 r;
            r.x = a0.x+a1.x+a2.x+a3.x; r.y = a0.y+a1.y+a2.y+a3.y;
            r.z = a0.z+a1.z+a2.z+a3.z; r.w = a0.w+a1.w+a2.w+a3.w;
            *(float4*)(hp + (size_t)ch*QQ + q0 + t*4) = r;
        }
    } else {
        // ---- data part: 128 cols x 32 batches, JCD rows ----
        const int idx  = bx - NH0;
        const int cb   = idx & 31;        // 128-col block
        const int cd   = idx >> 5;        // j-chunk
        const int q0   = cb*128;
        const int gate = q0 >> 10;        // block-uniform
        const int k0   = q0 & (HH-1);
        const float* w = (gate==0) ? wf : (gate==1) ? wi : (gate==2) ? wc : wo;
        const int jc0  = cd*JCD;

        for (int s = t; s < BB*JCD/4; s += 512) {
            const int b  = s / (JCD/4);
            const int jj = (s % (JCD/4))*4;
            const float4 v = *(const float4*)(data + (size_t)b*TT*FF + (size_t)(TT-1)*FF + jc0 + jj);
            lds[b*JCD + jj+0] = v.x; lds[b*JCD + jj+1] = v.y;
            lds[b*JCD + jj+2] = v.z; lds[b*JCD + jj+3] = v.w;
        }
        __syncthreads();

        const int c4 = t & 31;            // 4-col group (128 cols)
        const int b0 = (t >> 5) * 2;      // 2-batch group
        const int k4 = k0 + c4*4;
        float4 acc[2];
        acc[0] = make_float4(0.f,0.f,0.f,0.f);
        acc[1] = make_float4(0.f,0.f,0.f,0.f);

        #pragma unroll 2
        for (int j = 0; j < JCD; j += 4) {
            const float4 w0 = *(const float4*)(w + (size_t)(HH + jc0 + j+0)*HH + k4);
            const float4 w1 = *(const float4*)(w + (size_t)(HH + jc0 + j+1)*HH + k4);
            const float4 w2 = *(const float4*)(w + (size_t)(HH + jc0 + j+2)*HH + k4);
            const float4 w3 = *(const float4*)(w + (size_t)(HH + jc0 + j+3)*HH + k4);
            #pragma unroll
            for (int bi = 0; bi < 2; ++bi) {
                const float d0 = lds[(b0+bi)*JCD + j+0];
                const float d1 = lds[(b0+bi)*JCD + j+1];
                const float d2 = lds[(b0+bi)*JCD + j+2];
                const float d3 = lds[(b0+bi)*JCD + j+3];
                acc[bi].x += d0*w0.x; acc[bi].y += d0*w0.y; acc[bi].z += d0*w0.z; acc[bi].w += d0*w0.w;
                acc[bi].x += d1*w1.x; acc[bi].y += d1*w1.y; acc[bi].z += d1*w1.z; acc[bi].w += d1*w1.w;
                acc[bi].x += d2*w2.x; acc[bi].y += d2*w2.y; acc[bi].z += d2*w2.z; acc[bi].w += d2*w2.w;
                acc[bi].x += d3*w3.x; acc[bi].y += d3*w3.y; acc[bi].z += d3*w3.z; acc[bi].w += d3*w3.w;
            }
        }
        #pragma unroll
        for (int bi = 0; bi < 2; ++bi)
            *(float4*)(dp + ((size_t)cd*BB + b0 + bi)*QQ + q0 + c4*4) = acc[bi];
    }
}

// ---------------- Stage 2: reduce partials + gates -> h_last ----------------
// grid = (HH/256 = 4, BB), block = 256.  (round-18 exact)
template<int CH, int CD>
__global__ __launch_bounds__(256, 2) void k_cell(
    const float* __restrict__ hp, const float* __restrict__ dp,
    const float* __restrict__ c0, float* __restrict__ hlast)
{
    __shared__ float4 p[4][64];
    const int t    = threadIdx.x;
    const int kblk = blockIdx.x;
    const int b    = blockIdx.y;
    const int g    = t >> 6;
    const int i    = t & 63;
    const int q    = g*HH + kblk*256 + i*4;

    float4 s = make_float4(0.f,0.f,0.f,0.f);
    #pragma unroll 8
    for (int ch = 0; ch < CH; ++ch) {
        const float4 v = *(const float4*)(hp + (size_t)ch*QQ + q);
        s.x += v.x; s.y += v.y; s.z += v.z; s.w += v.w;
    }
    #pragma unroll 8
    for (int cd = 0; cd < CD; ++cd) {
        const float4 v = *(const float4*)(dp + ((size_t)cd*BB + b)*QQ + q);
        s.x += v.x; s.y += v.y; s.z += v.z; s.w += v.w;
    }
    p[g][i] = s;
    __syncthreads();

    if (t < 64) {
        const float4 gf = p[0][t], gi = p[1][t], gc = p[2][t], go = p[3][t];
        const float4 cv = *(const float4*)(c0 + kblk*256 + t*4);
        float4 h;
        { const float f=1.f/(1.f+expf(-gf.x)), ii=1.f/(1.f+expf(-gi.x)), cg=tanhf(gc.x), o=1.f/(1.f+expf(-go.x)); h.x=o*tanhf(f*cv.x+ii*cg); }
        { const float f=1.f/(1.f+expf(-gf.y)), ii=1.f/(1.f+expf(-gi.y)), cg=tanhf(gc.y), o=1.f/(1.f+expf(-go.y)); h.y=o*tanhf(f*cv.y+ii*cg); }
        { const float f=1.f/(1.f+expf(-gf.z)), ii=1.f/(1.f+expf(-gi.z)), cg=tanhf(gc.z), o=1.f/(1.f+expf(-go.z)); h.z=o*tanhf(f*cv.z+ii*cg); }
        { const float f=1.f/(1.f+expf(-gf.w)), ii=1.f/(1.f+expf(-gi.w)), cg=tanhf(gc.w), o=1.f/(1.f+expf(-go.w)); h.w=o*tanhf(f*cv.w+ii*cg); }
        *(float4*)(hlast + (size_t)b*HH + kblk*256 + t*4) = h;
    }
}

// ---------------- Stage 3a: fc partial GEMM (k-split, KCN=8) ----------------
// (round-18 exact)
__global__ __launch_bounds__(256) void k_fc_part(
    const float* __restrict__ hlast, const float* __restrict__ fcw,
    float* __restrict__ pl)
{
    __shared__ float hs[BB][KS+2];
    __shared__ float wl[FCB][KS+2];
    const int t  = threadIdx.x;
    const int c0 = blockIdx.x * FCB;
    const int kc = blockIdx.y;
    const int k0 = kc*KS;
    const int b  = t & 31;
    const int cl = t >> 5;
    const int c  = c0 + cl;

    for (int l = t; l < BB*(KS/4); l += 256) {
        const int bb = l >> 5, kk = l & 31;
        const float4 v = *(const float4*)(hlast + (size_t)bb*HH + k0 + kk*4);
        *(float2*)&hs[bb][kk*4+0] = make_float2(v.x, v.y);
        *(float2*)&hs[bb][kk*4+2] = make_float2(v.z, v.w);
    }
    for (int l = t; l < FCB*(KS/4); l += 256) {
        const int cc = l >> 5, kk = l & 31;
        const float4 v = *(const float4*)(fcw + (size_t)(c0+cc)*HH + k0 + kk*4);
        *(float2*)&wl[cc][kk*4+0] = make_float2(v.x, v.y);
        *(float2*)&wl[cc][kk*4+2] = make_float2(v.z, v.w);
    }
    __syncthreads();

    float acc = 0.f;
    #pragma unroll 16
    for (int k2 = 0; k2 < KS/2; ++k2) {
        const float2 h2 = *(const float2*)&hs[b][k2*2];
        const float2 w2 = *(const float2*)&wl[cl][k2*2];
        acc += h2.x*w2.x + h2.y*w2.y;
    }
    pl[((size_t)kc*BB + b)*CC + c] = acc;
}

// ---------------- Stage 3b: reduce k-split + bias + relu + log_softmax ----------------
// (round-18 exact)
__global__ __launch_bounds__(256) void k_lsm(
    const float* __restrict__ pl, const float* __restrict__ fcb,
    float* __restrict__ out)
{
    __shared__ float red[8];
    const int b = blockIdx.x, t = threadIdx.x;
    float v[4]; float vmax = -1e30f;
    #pragma unroll
    for (int ci = 0; ci < 4; ++ci) {
        const int c = t + ci*256;
        if (c < CC) {
            float s = fcb[c];
            #pragma unroll
            for (int kc = 0; kc < KCN; ++kc)
                s += pl[((size_t)kc*BB + b)*CC + c];
            v[ci] = fmaxf(s, 0.f);
            vmax = fmaxf(vmax, v[ci]);
        } else v[ci] = -1e30f;
    }
    for (int o = 32; o > 0; o >>= 1) vmax = fmaxf(vmax, __shfl_down(vmax, o, 64));
    const int lane = t & 63, wid = t >> 6;
    if (lane == 0) red[wid] = vmax;
    __syncthreads();
    if (t == 0) red[4] = fmaxf(fmaxf(red[0], red[1]), fmaxf(red[2], red[3]));
    __syncthreads();
    const float m = red[4];
    float se = 0.f;
    #pragma unroll
    for (int ci = 0; ci < 4; ++ci) {
        const int c = t + ci*256;
        if (c < CC) se += expf(v[ci] - m);
    }
    for (int o = 32; o > 0; o >>= 1) se += __shfl_down(se, o, 64);
    if (lane == 0) red[wid] = se;
    __syncthreads();
    if (t == 0) red[5] = m + logf(red[0] + red[1] + red[2] + red[3]);
    __syncthreads();
    const float lse = red[5];
    #pragma unroll
    for (int ci = 0; ci < 4; ++ci) {
        const int c = t + ci*256;
        if (c < CC) out[(size_t)b*CC + c] = v[ci] - lse;
    }
}

extern "C" void kernel_launch(void* const* d_in, const int* in_sizes, int n_in,
                              void* d_out, int out_size, void* d_ws, size_t ws_size,
                              hipStream_t stream) {
    const float* data = (const float*)d_in[0];
    const float* h0   = (const float*)d_in[1];
    const float* c0   = (const float*)d_in[2];
    const float* wf   = (const float*)d_in[3];
    const float* wi   = (const float*)d_in[4];
    const float* wc   = (const float*)d_in[5];
    const float* wo   = (const float*)d_in[6];
    const float* fcw  = (const float*)d_in[7];
    const float* fcb  = (const float*)d_in[8];
    float* out = (float*)d_out;

    // Config A: CHH=32, CHD=16 (JCD=32) -> ~9.7 MB ws; gates grid 256+512=768.
    // Config B: CHH=32, CHD=4  (JCD=128) -> ~3.7 MB ws; gates grid 256+128=384.
    const size_t needA = ((size_t)32*QQ + (size_t)16*BB*QQ + (size_t)BB*HH + (size_t)KCN*BB*CC) * 4;
    const bool cfgA = (ws_size >= needA);

    float* ws = (float*)d_ws;
    if (cfgA) {
        float* hp = ws;                               // 32*QQ
        float* dp = hp + (size_t)32*QQ;               // 16*BB*QQ
        float* hl = dp + (size_t)16*BB*QQ;            // BB*HH
        float* pl = hl + (size_t)BB*HH;               // KCN*BB*CC
        k_gates<32,32,16><<<dim3(8*32 + 32*16), 512, 0, stream>>>(data, h0, wf, wi, wc, wo, hp, dp);
        k_cell<32,16><<<dim3(HH/256, BB), 256, 0, stream>>>(hp, dp, c0, hl);
        k_fc_part<<<dim3(CC/FCB, KCN), 256, 0, stream>>>(hl, fcw, pl);
        k_lsm<<<dim3(BB), 256, 0, stream>>>(pl, fcb, out);
    } else {
        float* hp = ws;                               // 32*QQ
        float* dp = hp + (size_t)32*QQ;               // 4*BB*QQ
        float* hl = dp + (size_t)4*BB*QQ;             // BB*HH
        float* pl = hl + (size_t)BB*HH;               // KCN*BB*CC
        k_gates<32,128,4><<<dim3(8*32 + 32*4), 512, 0, stream>>>(data, h0, wf, wi, wc, wo, hp, dp);
        k_cell<32,4><<<dim3(HH/256, BB), 256, 0, stream>>>(hp, dp, c0, hl);
        k_fc_part<<<dim3(CC/FCB, KCN), 256, 0, stream>>>(hl, fcw, pl);
        k_lsm<<<dim3(BB), 256, 0, stream>>>(pl, fcb, out);
    }
}